// Round 1
// 285.332 us; speedup vs baseline: 1.0439x; 1.0439x over previous
//
#include <hip/hip_runtime.h>
#include <math.h>

#define B 8
#define S 1024
#define HID 1024
#define HEADS 16
#define DK 64

typedef unsigned short u16;
typedef unsigned int u32;
typedef _Float16 f16;
typedef __attribute__((ext_vector_type(8))) _Float16 half8;
typedef __attribute__((ext_vector_type(4))) _Float16 half4;
typedef __attribute__((ext_vector_type(2))) _Float16 half2;
typedef __attribute__((ext_vector_type(2))) __fp16 fp16x2;
typedef __attribute__((ext_vector_type(4))) float f32x4;

// async global->LDS, 16B/lane. LDS dest is wave-uniform base + lane*16.
#define GLL16(G, L)                                                         \
    __builtin_amdgcn_global_load_lds(                                       \
        (const __attribute__((address_space(1))) u32*)(G),                  \
        (__attribute__((address_space(3))) u32*)(L), 16, 0, 0)

// Q is pre-scaled by log2(e)/8 at the projection epilogue, so
// exp(QK/8) == exp2(c) directly — saves one v_mul per exp.
__device__ __forceinline__ float exp_s(float c) {
#if __has_builtin(__builtin_amdgcn_exp2f)
    return __builtin_amdgcn_exp2f(c);
#else
    return exp2f(c);
#endif
}

// ---------------------------------------------------------------------------
// Fused cast: q,k,v (B*S*HID each) + Wq,Wk,Wv (HID*HID each) fp32 -> f16.
// ---------------------------------------------------------------------------
__global__ __launch_bounds__(256) void cast_all(
    const float* __restrict__ q, const float* __restrict__ k,
    const float* __restrict__ v, const float* __restrict__ Wq,
    const float* __restrict__ Wk, const float* __restrict__ Wv,
    f16* __restrict__ oq, f16* __restrict__ ok, f16* __restrict__ ov,
    f16* __restrict__ owq, f16* __restrict__ owk, f16* __restrict__ owv) {
    const size_t SZ = (size_t)B * S * HID;
    const size_t WZ = (size_t)HID * HID;
    size_t e = ((size_t)blockIdx.x * 256 + threadIdx.x) * 8;
    const float* src;
    f16* dst;
    if (e < SZ)               { src = q + e;               dst = oq + e; }
    else if (e < 2 * SZ)      { src = k + (e - SZ);        dst = ok + (e - SZ); }
    else if (e < 3 * SZ)      { src = v + (e - 2 * SZ);    dst = ov + (e - 2 * SZ); }
    else if (e < 3 * SZ + WZ) { src = Wq + (e - 3 * SZ);   dst = owq + (e - 3 * SZ); }
    else if (e < 3 * SZ + 2 * WZ) { src = Wk + (e - 3 * SZ - WZ); dst = owk + (e - 3 * SZ - WZ); }
    else                      { src = Wv + (e - 3 * SZ - 2 * WZ); dst = owv + (e - 3 * SZ - 2 * WZ); }
    f32x4 a = *(const f32x4*)src;
    f32x4 b = *(const f32x4*)(src + 4);
    half8 h;
    h[0] = (f16)a[0]; h[1] = (f16)a[1]; h[2] = (f16)a[2]; h[3] = (f16)a[3];
    h[4] = (f16)b[0]; h[5] = (f16)b[1]; h[6] = (f16)b[2]; h[7] = (f16)b[3];
    *(half8*)dst = h;
}

// ---------------------------------------------------------------------------
// Batched projection GEMM (m97 pattern): C = X @ W^T, f16, 3 GEMMs in one
// 1536-block 1D launch, XCD-swizzled. 128x128 tile, BK=32, 4 waves 64x64.
// z==0 (Q) output is pre-scaled by log2(e)/8 so downstream exp is bare exp2.
// ---------------------------------------------------------------------------
__global__ __launch_bounds__(256) void proj_mfma_b(
    const f16* __restrict__ Xq, const f16* __restrict__ Xk,
    const f16* __restrict__ Xv, const f16* __restrict__ Wq,
    const f16* __restrict__ Wk, const f16* __restrict__ Wv,
    f16* __restrict__ Qb, f16* __restrict__ Kb, f16* __restrict__ Vt) {
    const int L = blockIdx.x;          // 0..1535
    const int xcd = L & 7;
    const int w8 = L >> 3;             // 0..191
    const int cx = w8 & 7;             // column tile 0..7
    const int g = xcd * 24 + (w8 >> 3);// 0..191 unique (z, ytile)
    const int z = g % 3;
    const int ytile = g / 3;           // 0..63

    const f16* __restrict__ X = (z == 0) ? Xq : (z == 1) ? Xk : Xv;
    const f16* __restrict__ W = (z == 0) ? Wq : (z == 1) ? Wk : Wv;

    __shared__ u16 As[128 * 32];
    __shared__ u16 Bs[128 * 32];
    const int tid = threadIdx.x;
    const int wv = tid >> 6, ln = tid & 63;
    const int lr = ln & 15, quad = ln >> 4;
    const int wm = wv >> 1, wn = wv & 1;
    const int row0 = ytile * 128, col0 = cx * 128;

    const int srow = tid >> 2;       // 0..63 (rows per staging call)
    const int sch = tid & 3;         // chunk-of-8 within 32-k row

    f32x4 acc[4][4];
    #pragma unroll
    for (int i = 0; i < 4; ++i)
        #pragma unroll
        for (int j = 0; j < 4; ++j) acc[i][j] = (f32x4){0.f, 0.f, 0.f, 0.f};

    for (int k0 = 0; k0 < HID; k0 += 32) {
        #pragma unroll
        for (int p = 0; p < 2; ++p) {
            int r = p * 64 + srow;
            int csw = sch ^ ((r >> 1) & 3);
            GLL16(X + (size_t)(row0 + r) * HID + k0 + csw * 8, As + p * 2048 + tid * 8);
            GLL16(W + (size_t)(col0 + r) * HID + k0 + csw * 8, Bs + p * 2048 + tid * 8);
        }
        __syncthreads();
        half8 a[4], b[4];
        #pragma unroll
        for (int mi = 0; mi < 4; ++mi) {
            int r = wm * 64 + mi * 16 + lr;
            a[mi] = *(const half8*)(As + r * 32 + ((quad ^ ((r >> 1) & 3)) * 8));
        }
        #pragma unroll
        for (int ni = 0; ni < 4; ++ni) {
            int r = wn * 64 + ni * 16 + lr;
            b[ni] = *(const half8*)(Bs + r * 32 + ((quad ^ ((r >> 1) & 3)) * 8));
        }
        #pragma unroll
        for (int mi = 0; mi < 4; ++mi)
            #pragma unroll
            for (int ni = 0; ni < 4; ++ni)
                acc[mi][ni] = __builtin_amdgcn_mfma_f32_16x16x32_f16(
                    a[mi], b[ni], acc[mi][ni], 0, 0, 0);
        __syncthreads();
    }

    if (z < 2) {
        f16* __restrict__ Y = (z == 0) ? Qb : Kb;
        const float sc = (z == 0) ? 0.18033688f : 1.0f;  // log2(e)/8 baked into Q
        #pragma unroll
        for (int mi = 0; mi < 4; ++mi) {
            int m = row0 + wm * 64 + mi * 16 + quad * 4;
            #pragma unroll
            for (int ni = 0; ni < 4; ++ni) {
                int n = col0 + wn * 64 + ni * 16 + lr;
                #pragma unroll
                for (int r = 0; r < 4; ++r)
                    Y[(size_t)(m + r) * HID + n] = (f16)(acc[mi][ni][r] * sc);
            }
        }
    } else {
        #pragma unroll
        for (int mi = 0; mi < 4; ++mi) {
            int m = row0 + wm * 64 + mi * 16 + quad * 4;   // s index (4 packed)
            int bb = m >> 10, s = m & 1023;
            #pragma unroll
            for (int ni = 0; ni < 4; ++ni) {
                int n = col0 + wn * 64 + ni * 16 + lr;     // hid index
                half4 h4;
                #pragma unroll
                for (int r = 0; r < 4; ++r) h4[r] = (f16)acc[mi][ni][r];
                *(half4*)(Vt + ((size_t)(bb * 16 + (n >> 6)) * 64 + (n & 63)) * S + s) = h4;
            }
        }
    }
}

// ---------------------------------------------------------------------------
// Stats + V-scale: rl_j = 1 / sum_i exp2(Q'_j.K_i); then Vt[:, j] *= rl_j.
// DOUBLE-BUFFERED K staging: one barrier per 64-i tile; next tile's GLL16
// issued BEFORE the current tile's compute so global->LDS latency hides
// under the MFMA+exp work (T3 minimum 2-phase recipe).
// ---------------------------------------------------------------------------
__global__ __launch_bounds__(256) void stats_mfma(const f16* __restrict__ Q,
                                                  const f16* __restrict__ K,
                                                  f16* __restrict__ Vt) {
    const int bh = blockIdx.x, jt = blockIdx.y;
    const int b = bh >> 4, h = bh & 15;
    const int tid = threadIdx.x;
    const int wv = tid >> 6, ln = tid & 63;
    const int lr = ln & 15, quad = ln >> 4;
    __shared__ u16 Ks[2][64 * 64];    // 16 KB (double-buffered)
    __shared__ float rlL[128];

    auto stageK = [&](int bufi, int i0v) {
        #pragma unroll
        for (int p = 0; p < 2; ++p) {
            int r = p * 32 + (tid >> 3);
            int csw = (tid & 7) ^ (r & 7);
            GLL16(K + (size_t)(b * S + i0v + r) * HID + h * 64 + csw * 8,
                  Ks[bufi] + p * 2048 + tid * 8);
        }
    };

    stageK(0, 0);   // prefetch tile 0; latency hides under the aq loads below

    // A-fragments (Q rows) straight from global: A[m=lr][k=kf*32+quad*8..]
    half8 aq[2][2];
    #pragma unroll
    for (int jsub = 0; jsub < 2; ++jsub) {
        const int j = jt * 128 + wv * 32 + jsub * 16 + lr;
        const f16* qrow = Q + (size_t)(b * S + j) * HID + h * 64;
        aq[jsub][0] = *(const half8*)(qrow + quad * 8);
        aq[jsub][1] = *(const half8*)(qrow + 32 + quad * 8);
    }

    float sl[2][4] = {};

    for (int t = 0; t < S / 64; ++t) {
        __syncthreads();                       // tile t staged; buffers swapped
        if (t + 1 < S / 64) stageK((t + 1) & 1, (t + 1) * 64);
        const u16* Kst = Ks[t & 1];
        #pragma unroll
        for (int isub = 0; isub < 4; ++isub) {
            int il = isub * 16 + lr;
            half8 bk0 = *(const half8*)(Kst + il * 64 + (((0 + quad) ^ (il & 7)) * 8));
            half8 bk1 = *(const half8*)(Kst + il * 64 + (((4 + quad) ^ (il & 7)) * 8));
            #pragma unroll
            for (int jsub = 0; jsub < 2; ++jsub) {
                f32x4 c = {0.f, 0.f, 0.f, 0.f};
                c = __builtin_amdgcn_mfma_f32_16x16x32_f16(aq[jsub][0], bk0, c, 0, 0, 0);
                c = __builtin_amdgcn_mfma_f32_16x16x32_f16(aq[jsub][1], bk1, c, 0, 0, 0);
                #pragma unroll
                for (int r = 0; r < 4; ++r) sl[jsub][r] += exp_s(c[r]);
            }
        }
    }

    // C layout: row j = wv*32 + jsub*16 + quad*4 + r; reduce over lr lanes
    #pragma unroll
    for (int jsub = 0; jsub < 2; ++jsub)
        #pragma unroll
        for (int r = 0; r < 4; ++r) {
            float v = sl[jsub][r];
            v += __shfl_xor(v, 1, 64);
            v += __shfl_xor(v, 2, 64);
            v += __shfl_xor(v, 4, 64);
            v += __shfl_xor(v, 8, 64);
            if (lr == 0) rlL[wv * 32 + jsub * 16 + quad * 4 + r] = 1.0f / v;
        }
    __syncthreads();

    // scale Vt[:, jt*128 .. +128] in place; lanes (tid&3) now read a
    // CONTIGUOUS 64B run per instruction (was 16B chunks at 64B stride)
    {
        const int d = tid >> 2, lc = (tid & 3) * 8;
        f16* vrow = Vt + (size_t)(bh * 64 + d) * S + jt * 128;
        #pragma unroll
        for (int g = 0; g < 4; ++g) {
            const int c0 = g * 32 + lc;
            half8 hv = *(half8*)(vrow + c0);
            #pragma unroll
            for (int e = 0; e < 8; ++e)
                hv[e] = (f16)((float)hv[e] * rlL[c0 + e]);
            *(half8*)(vrow + c0) = hv;
        }
    }
}

// ---------------------------------------------------------------------------
// Apply: out[i,d] = sum_{j<=i} exp2(K_i.Q'_j) * V'[j,d]  (V' pre-scaled).
// DOUBLE-BUFFERED Q/Vt staging: one barrier per 64-j chunk; chunk jc+1's
// GLL16 issued before chunk jc's compute.
// ---------------------------------------------------------------------------
__global__ __launch_bounds__(256) void apply_mfma(const f16* __restrict__ Q,
                                                  const f16* __restrict__ K,
                                                  const f16* __restrict__ Vt,
                                                  float* __restrict__ out) {
    const int bh = blockIdx.x;
    const int it2 = (gridDim.y - 1) - blockIdx.y;   // heavy blocks first
    const int b = bh >> 4, h = bh & 15;
    const int tid = threadIdx.x;
    const int wv = tid >> 6, ln = tid & 63;
    const int lr = ln & 15, quad = ln >> 4;
    const int i0b = it2 * 128;
    const int i0w = i0b + wv * 32;

    __shared__ u16 Qs[2][64 * 64];    // 16 KB
    __shared__ u16 Vts[2][64 * 64];   // 16 KB

    auto stageQV = [&](int bufi, int j0v) {
        #pragma unroll
        for (int p = 0; p < 2; ++p) {   // Qs: 64 rows x 64 f16
            int r = p * 32 + (tid >> 3);
            int csw = (tid & 7) ^ (r & 7);
            GLL16(Q + (size_t)(b * S + j0v + r) * HID + h * 64 + csw * 8,
                  Qs[bufi] + p * 2048 + tid * 8);
        }
        #pragma unroll
        for (int p = 0; p < 2; ++p) {   // Vts: 64 d-rows x 64 j
            int d = p * 32 + (tid >> 3);
            int csw = (tid & 7) ^ (d & 7);
            GLL16(Vt + (size_t)(bh * 64 + d) * S + j0v + csw * 8,
                  Vts[bufi] + p * 2048 + tid * 8);
        }
    };

    stageQV(0, 0);   // prefetch chunk 0; hides under the bk loads below

    // K B-fragments (fixed per wave): B[n=i][k], k = kf*32 + quad*8
    half8 bk[2][2];
    #pragma unroll
    for (int isub = 0; isub < 2; ++isub) {
        int i = i0w + isub * 16 + lr;
        #pragma unroll
        for (int kf = 0; kf < 2; ++kf)
            bk[isub][kf] = *(const half8*)(K + (size_t)(b * S + i) * HID + h * 64 +
                                           kf * 32 + quad * 8);
    }

    f32x4 acc[4][2];
    #pragma unroll
    for (int nt = 0; nt < 4; ++nt)
        #pragma unroll
        for (int isub = 0; isub < 2; ++isub) acc[nt][isub] = (f32x4){0.f, 0.f, 0.f, 0.f};

    const int nch = 2 * it2 + 2;
    for (int jc = 0; jc < nch; ++jc) {
        const int j0 = jc * 64;
        __syncthreads();                        // chunk jc staged
        if (jc + 1 < nch) stageQV((jc + 1) & 1, j0 + 64);
        const u16* Qsc = Qs[jc & 1];
        const u16* Vsc = Vts[jc & 1];

        #pragma unroll
        for (int jsub = 0; jsub < 4; ++jsub) {
            const int jbase = j0 + jsub * 16;
            if (jbase > i0w + 31) break;   // this and later jsubs fully masked

            const int jl = jsub * 16 + lr;
            half8 aq0 = *(const half8*)(Qsc + jl * 64 + (((0 + quad) ^ (jl & 7)) * 8));
            half8 aq1 = *(const half8*)(Qsc + jl * 64 + (((4 + quad) ^ (jl & 7)) * 8));
            half4 av[4];
            #pragma unroll
            for (int nt = 0; nt < 4; ++nt) {
                int d = nt * 16 + lr;
                int ch = (jsub * 2 + (quad >> 1)) ^ (d & 7);
                av[nt] = *(const half4*)(Vsc + d * 64 + ch * 8 + (quad & 1) * 4);
            }

            #pragma unroll
            for (int isub = 0; isub < 2; ++isub) {
                const int ib = i0w + isub * 16;
                if (jbase > ib + 15) continue;     // tile fully above diagonal
                f32x4 c = {0.f, 0.f, 0.f, 0.f};
                c = __builtin_amdgcn_mfma_f32_16x16x32_f16(aq0, bk[isub][0], c, 0, 0, 0);
                c = __builtin_amdgcn_mfma_f32_16x16x32_f16(aq1, bk[isub][1], c, 0, 0, 0);
                float w0 = exp_s(c[0]), w1 = exp_s(c[1]);
                float w2 = exp_s(c[2]), w3 = exp_s(c[3]);
                if (jbase + 15 > ib) {             // diagonal tile: mask j > i
                    const int i_col = ib + lr;
                    const int jq = jbase + quad * 4;
                    if (jq + 0 > i_col) w0 = 0.f;
                    if (jq + 1 > i_col) w1 = 0.f;
                    if (jq + 2 > i_col) w2 = 0.f;
                    if (jq + 3 > i_col) w3 = 0.f;
                }
                fp16x2 q0 = __builtin_amdgcn_cvt_pkrtz(w0, w1);
                fp16x2 q1 = __builtin_amdgcn_cvt_pkrtz(w2, w3);
                half2 p0 = __builtin_bit_cast(half2, q0);
                half2 p1 = __builtin_bit_cast(half2, q1);
                half4 bw;
                bw[0] = p0[0]; bw[1] = p0[1]; bw[2] = p1[0]; bw[3] = p1[1];
                #pragma unroll
                for (int nt = 0; nt < 4; ++nt)
                    acc[nt][isub] = __builtin_amdgcn_mfma_f32_16x16x16f16(
                        av[nt], bw, acc[nt][isub], 0, 0, 0);
            }
        }
    }

    // epilogue: acc holds out^T[d][i]; row=d=nt*16+quad*4+r, col=i (lr)
    #pragma unroll
    for (int isub = 0; isub < 2; ++isub) {
        int i = i0w + isub * 16 + lr;
        #pragma unroll
        for (int nt = 0; nt < 4; ++nt)
            *(f32x4*)(out + (size_t)(b * S + i) * HID + h * 64 + nt * 16 + quad * 4) =
                acc[nt][isub];
    }
}

// ---------------------------------------------------------------------------
extern "C" void kernel_launch(void* const* d_in, const int* in_sizes, int n_in,
                              void* d_out, int out_size, void* d_ws, size_t ws_size,
                              hipStream_t stream) {
    const float* q  = (const float*)d_in[0];
    const float* k  = (const float*)d_in[1];
    const float* v  = (const float*)d_in[2];
    const float* Wq = (const float*)d_in[3];
    const float* Wk = (const float*)d_in[4];
    const float* Wv = (const float*)d_in[5];

    const size_t SZ = (size_t)B * S * HID;   // 8,388,608
    const size_t WZ = (size_t)HID * HID;     // 1,048,576

    // q/k f16 casts live inside d_out (32 MB = 2*SZ f16), consumed by proj
    // before apply overwrites d_out. v/W casts + Q/K/Vt live in ws (~70 MB).
    f16* xq = (f16*)d_out;
    f16* xk = xq + SZ;

    char* p = (char*)d_ws;
    f16* xv = (f16*)p;      p += SZ * 2;
    f16* wq = (f16*)p;      p += WZ * 2;
    f16* wk = (f16*)p;      p += WZ * 2;
    f16* wv_ = (f16*)p;     p += WZ * 2;
    f16* Qb = (f16*)p;      p += SZ * 2;
    f16* Kb = (f16*)p;      p += SZ * 2;
    f16* Vt = (f16*)p;      p += SZ * 2;

    float* out = (float*)d_out;

    const int ncast = (int)((3 * SZ + 3 * WZ) / 8 / 256);   // 13824 blocks
    cast_all<<<ncast, 256, 0, stream>>>(q, k, v, Wq, Wk, Wv,
                                        xq, xk, xv, wq, wk, wv_);

    // 3 GEMMs in one 1536-block launch, XCD-swizzled inside the kernel
    proj_mfma_b<<<1536, 256, 0, stream>>>(xq, xk, xv, wq, wk, wv_, Qb, Kb, Vt);

    stats_mfma<<<dim3(B * HEADS, S / 128), 256, 0, stream>>>(Qb, Kb, Vt);
    apply_mfma<<<dim3(B * HEADS, S / 128), 256, 0, stream>>>(Qb, Kb, Vt, out);
}

// Round 2
// 280.008 us; speedup vs baseline: 1.0637x; 1.0190x over previous
//
#include <hip/hip_runtime.h>
#include <math.h>

#define B 8
#define S 1024
#define HID 1024
#define HEADS 16
#define DK 64

typedef unsigned short u16;
typedef unsigned int u32;
typedef _Float16 f16;
typedef __attribute__((ext_vector_type(8))) _Float16 half8;
typedef __attribute__((ext_vector_type(4))) _Float16 half4;
typedef __attribute__((ext_vector_type(2))) _Float16 half2;
typedef __attribute__((ext_vector_type(2))) __fp16 fp16x2;
typedef __attribute__((ext_vector_type(4))) float f32x4;

// async global->LDS, 16B/lane. LDS dest is wave-uniform base + lane*16.
#define GLL16(G, L)                                                         \
    __builtin_amdgcn_global_load_lds(                                       \
        (const __attribute__((address_space(1))) u32*)(G),                  \
        (__attribute__((address_space(3))) u32*)(L), 16, 0, 0)

#define MF32(a, b, c) __builtin_amdgcn_mfma_f32_16x16x32_f16((a), (b), (c), 0, 0, 0)

// Q is pre-scaled by log2(e)/8 at the projection epilogue, so
// exp(QK/8) == exp2(c) directly — saves one v_mul per exp.
__device__ __forceinline__ float exp_s(float c) {
#if __has_builtin(__builtin_amdgcn_exp2f)
    return __builtin_amdgcn_exp2f(c);
#else
    return exp2f(c);
#endif
}

// ---------------------------------------------------------------------------
// Fused cast: q,k,v (B*S*HID each) + Wq,Wk,Wv (HID*HID each) fp32 -> f16.
// ---------------------------------------------------------------------------
__global__ __launch_bounds__(256) void cast_all(
    const float* __restrict__ q, const float* __restrict__ k,
    const float* __restrict__ v, const float* __restrict__ Wq,
    const float* __restrict__ Wk, const float* __restrict__ Wv,
    f16* __restrict__ oq, f16* __restrict__ ok, f16* __restrict__ ov,
    f16* __restrict__ owq, f16* __restrict__ owk, f16* __restrict__ owv) {
    const size_t SZ = (size_t)B * S * HID;
    const size_t WZ = (size_t)HID * HID;
    size_t e = ((size_t)blockIdx.x * 256 + threadIdx.x) * 8;
    const float* src;
    f16* dst;
    if (e < SZ)               { src = q + e;               dst = oq + e; }
    else if (e < 2 * SZ)      { src = k + (e - SZ);        dst = ok + (e - SZ); }
    else if (e < 3 * SZ)      { src = v + (e - 2 * SZ);    dst = ov + (e - 2 * SZ); }
    else if (e < 3 * SZ + WZ) { src = Wq + (e - 3 * SZ);   dst = owq + (e - 3 * SZ); }
    else if (e < 3 * SZ + 2 * WZ) { src = Wk + (e - 3 * SZ - WZ); dst = owk + (e - 3 * SZ - WZ); }
    else                      { src = Wv + (e - 3 * SZ - 2 * WZ); dst = owv + (e - 3 * SZ - 2 * WZ); }
    f32x4 a = *(const f32x4*)src;
    f32x4 b = *(const f32x4*)(src + 4);
    half8 h;
    h[0] = (f16)a[0]; h[1] = (f16)a[1]; h[2] = (f16)a[2]; h[3] = (f16)a[3];
    h[4] = (f16)b[0]; h[5] = (f16)b[1]; h[6] = (f16)b[2]; h[7] = (f16)b[3];
    *(half8*)dst = h;
}

// ---------------------------------------------------------------------------
// Batched projection GEMM, 8-phase pipelined (T2+T3+T4+T5): C = X @ W^T, f16.
// BM=256 BN=128 BK=64, 8 waves (512 thr, wave = 64x64 out), LDS triple-buffer
// (3 x 48 KB = 144 KB), prefetch depth 2 K-tiles, counted s_waitcnt vmcnt(6)
// once per K-tile (never 0 in steady state), raw s_barrier (no __syncthreads
// vmcnt drain), setprio(1) around MFMA clusters.
// Grid: 3 z * 32 ytiles * 8 xtiles = 768 = 3 clean rounds of 1 block/CU.
// XCD swizzle bijective (768 % 8 == 0). z==0 (Q) output pre-scaled log2(e)/8.
// LDS swizzle: physical 16B-chunk c holds global chunk c ^ (row & 7)
// (pre-swizzled global source + linear GLL16 dest + swizzled ds_read).
// ---------------------------------------------------------------------------
__global__ __launch_bounds__(512, 2) void proj_mfma_b(
    const f16* __restrict__ Xq, const f16* __restrict__ Xk,
    const f16* __restrict__ Xv, const f16* __restrict__ Wq,
    const f16* __restrict__ Wk, const f16* __restrict__ Wv,
    f16* __restrict__ Qb, f16* __restrict__ Kb, f16* __restrict__ Vt) {
    const int L = blockIdx.x;                 // 0..767
    const int wg = (L & 7) * 96 + (L >> 3);   // bijective XCD chunking
    const int z = wg >> 8;                    // 0..2
    const int rm = wg & 255;
    const int ytile = rm >> 3;                // 0..31
    const int cx = rm & 7;                    // 0..7

    const f16* __restrict__ X = (z == 0) ? Xq : (z == 1) ? Xk : Xv;
    const f16* __restrict__ W = (z == 0) ? Wq : (z == 1) ? Wk : Wv;
    const int row0 = ytile * 256, col0 = cx * 128;

    __shared__ u16 As[3][256 * 64];   // 3 x 32 KB
    __shared__ u16 Bs[3][128 * 64];   // 3 x 16 KB

    const int tid = threadIdx.x;
    const int wv = tid >> 6, ln = tid & 63;
    const int lr = ln & 15, quad = ln >> 4;
    const int wm = wv >> 1, wn = wv & 1;      // 4M x 2N waves
    const int rr = tid >> 3, ch = tid & 7;    // staging row/chunk

    // stage K-tile kt into buffer bi: 6 GLL16 per thread (4 A + 2 B)
    auto stage = [&](int kt, int bi) {
        const f16* Xb = X + (size_t)row0 * HID + kt * 64;
        const f16* Wb = W + (size_t)col0 * HID + kt * 64;
        #pragma unroll
        for (int p = 0; p < 4; ++p) {
            int row = p * 64 + rr;
            GLL16(Xb + (size_t)row * HID + ((ch ^ (row & 7)) * 8),
                  &As[bi][p * 4096 + tid * 8]);
        }
        #pragma unroll
        for (int p = 0; p < 2; ++p) {
            int row = p * 64 + rr;
            GLL16(Wb + (size_t)row * HID + ((ch ^ (row & 7)) * 8),
                  &Bs[bi][p * 4096 + tid * 8]);
        }
    };

    f32x4 acc[4][4];
    #pragma unroll
    for (int i = 0; i < 4; ++i)
        #pragma unroll
        for (int j = 0; j < 4; ++j) acc[i][j] = (f32x4){0.f, 0.f, 0.f, 0.f};

    stage(0, 0);
    stage(1, 1);
    asm volatile("s_waitcnt vmcnt(6)" ::: "memory");   // tile 0 landed
    __builtin_amdgcn_s_barrier();

    int bi = 0, sbi = 2;
    #pragma unroll
    for (int u = 0; u < 16; ++u) {
        const u16* A = As[bi];
        const u16* Bh = Bs[bi];
        auto rdA = [&](int mi, int ks) -> half8 {
            int row = wm * 64 + mi * 16 + lr;
            int pc = (ks * 4 + quad) ^ (row & 7);
            return *(const half8*)(A + row * 64 + pc * 8);
        };
        auto rdB = [&](int ni, int ks) -> half8 {
            int row = wn * 64 + ni * 16 + lr;
            int pc = (ks * 4 + quad) ^ (row & 7);
            return *(const half8*)(Bh + row * 64 + pc * 8);
        };

        // ---- P0: quadrant (mi 0-1, ni 0-1); issue prefetch of tile u+2
        if (u < 14) stage(u + 2, sbi);
        half8 a00 = rdA(0, 0), a01 = rdA(0, 1), a10 = rdA(1, 0), a11 = rdA(1, 1);
        half8 b00 = rdB(0, 0), b01 = rdB(0, 1), b10 = rdB(1, 0), b11 = rdB(1, 1);
        __builtin_amdgcn_s_barrier();
        asm volatile("s_waitcnt lgkmcnt(0)" ::: "memory");
        __builtin_amdgcn_s_setprio(1);
        acc[0][0] = MF32(a00, b00, acc[0][0]); acc[0][0] = MF32(a01, b01, acc[0][0]);
        acc[0][1] = MF32(a00, b10, acc[0][1]); acc[0][1] = MF32(a01, b11, acc[0][1]);
        acc[1][0] = MF32(a10, b00, acc[1][0]); acc[1][0] = MF32(a11, b01, acc[1][0]);
        acc[1][1] = MF32(a10, b10, acc[1][1]); acc[1][1] = MF32(a11, b11, acc[1][1]);
        __builtin_amdgcn_s_setprio(0);
        __builtin_amdgcn_s_barrier();

        // ---- P1: quadrant (mi 0-1, ni 2-3)
        half8 b20 = rdB(2, 0), b21 = rdB(2, 1), b30 = rdB(3, 0), b31 = rdB(3, 1);
        __builtin_amdgcn_s_barrier();
        asm volatile("s_waitcnt lgkmcnt(0)" ::: "memory");
        __builtin_amdgcn_s_setprio(1);
        acc[0][2] = MF32(a00, b20, acc[0][2]); acc[0][2] = MF32(a01, b21, acc[0][2]);
        acc[0][3] = MF32(a00, b30, acc[0][3]); acc[0][3] = MF32(a01, b31, acc[0][3]);
        acc[1][2] = MF32(a10, b20, acc[1][2]); acc[1][2] = MF32(a11, b21, acc[1][2]);
        acc[1][3] = MF32(a10, b30, acc[1][3]); acc[1][3] = MF32(a11, b31, acc[1][3]);
        __builtin_amdgcn_s_setprio(0);
        __builtin_amdgcn_s_barrier();

        // ---- P2: quadrant (mi 2-3, ni 2-3)
        half8 a20 = rdA(2, 0), a21 = rdA(2, 1), a30 = rdA(3, 0), a31 = rdA(3, 1);
        __builtin_amdgcn_s_barrier();
        asm volatile("s_waitcnt lgkmcnt(0)" ::: "memory");
        __builtin_amdgcn_s_setprio(1);
        acc[2][2] = MF32(a20, b20, acc[2][2]); acc[2][2] = MF32(a21, b21, acc[2][2]);
        acc[2][3] = MF32(a20, b30, acc[2][3]); acc[2][3] = MF32(a21, b31, acc[2][3]);
        acc[3][2] = MF32(a30, b20, acc[3][2]); acc[3][2] = MF32(a31, b21, acc[3][2]);
        acc[3][3] = MF32(a30, b30, acc[3][3]); acc[3][3] = MF32(a31, b31, acc[3][3]);
        __builtin_amdgcn_s_setprio(0);
        __builtin_amdgcn_s_barrier();

        // ---- P3: quadrant (mi 2-3, ni 0-1), no new reads; counted vmcnt
        __builtin_amdgcn_s_setprio(1);
        acc[2][0] = MF32(a20, b00, acc[2][0]); acc[2][0] = MF32(a21, b01, acc[2][0]);
        acc[2][1] = MF32(a20, b10, acc[2][1]); acc[2][1] = MF32(a21, b11, acc[2][1]);
        acc[3][0] = MF32(a30, b00, acc[3][0]); acc[3][0] = MF32(a31, b01, acc[3][0]);
        acc[3][1] = MF32(a30, b10, acc[3][1]); acc[3][1] = MF32(a31, b11, acc[3][1]);
        __builtin_amdgcn_s_setprio(0);
        if (u < 14) {
            asm volatile("s_waitcnt vmcnt(6)" ::: "memory");   // tile u+1 landed
        } else if (u == 14) {
            asm volatile("s_waitcnt vmcnt(0)" ::: "memory");   // final drain
        }
        __builtin_amdgcn_s_barrier();

        bi = (bi + 1 == 3) ? 0 : bi + 1;
        sbi = (sbi + 1 == 3) ? 0 : sbi + 1;
    }

    if (z < 2) {
        f16* __restrict__ Y = (z == 0) ? Qb : Kb;
        const float sc = (z == 0) ? 0.18033688f : 1.0f;  // log2(e)/8 baked into Q
        #pragma unroll
        for (int mi = 0; mi < 4; ++mi) {
            int m = row0 + wm * 64 + mi * 16 + quad * 4;
            #pragma unroll
            for (int ni = 0; ni < 4; ++ni) {
                int n = col0 + wn * 64 + ni * 16 + lr;
                #pragma unroll
                for (int r = 0; r < 4; ++r)
                    Y[(size_t)(m + r) * HID + n] = (f16)(acc[mi][ni][r] * sc);
            }
        }
    } else {
        #pragma unroll
        for (int mi = 0; mi < 4; ++mi) {
            int m = row0 + wm * 64 + mi * 16 + quad * 4;   // s index (4 packed)
            int bb = m >> 10, s = m & 1023;
            #pragma unroll
            for (int ni = 0; ni < 4; ++ni) {
                int n = col0 + wn * 64 + ni * 16 + lr;     // hid index
                half4 h4;
                #pragma unroll
                for (int r = 0; r < 4; ++r) h4[r] = (f16)acc[mi][ni][r];
                *(half4*)(Vt + ((size_t)(bb * 16 + (n >> 6)) * 64 + (n & 63)) * S + s) = h4;
            }
        }
    }
}

// ---------------------------------------------------------------------------
// Stats + V-scale: rl_j = 1 / sum_i exp2(Q'_j.K_i); then Vt[:, j] *= rl_j.
// Double-buffered K staging (prefetch before compute).
// ---------------------------------------------------------------------------
__global__ __launch_bounds__(256) void stats_mfma(const f16* __restrict__ Q,
                                                  const f16* __restrict__ K,
                                                  f16* __restrict__ Vt) {
    const int bh = blockIdx.x, jt = blockIdx.y;
    const int b = bh >> 4, h = bh & 15;
    const int tid = threadIdx.x;
    const int wv = tid >> 6, ln = tid & 63;
    const int lr = ln & 15, quad = ln >> 4;
    __shared__ u16 Ks[2][64 * 64];    // 16 KB (double-buffered)
    __shared__ float rlL[128];

    auto stageK = [&](int bufi, int i0v) {
        #pragma unroll
        for (int p = 0; p < 2; ++p) {
            int r = p * 32 + (tid >> 3);
            int csw = (tid & 7) ^ (r & 7);
            GLL16(K + (size_t)(b * S + i0v + r) * HID + h * 64 + csw * 8,
                  Ks[bufi] + p * 2048 + tid * 8);
        }
    };

    stageK(0, 0);   // prefetch tile 0; latency hides under the aq loads below

    // A-fragments (Q rows) straight from global: A[m=lr][k=kf*32+quad*8..]
    half8 aq[2][2];
    #pragma unroll
    for (int jsub = 0; jsub < 2; ++jsub) {
        const int j = jt * 128 + wv * 32 + jsub * 16 + lr;
        const f16* qrow = Q + (size_t)(b * S + j) * HID + h * 64;
        aq[jsub][0] = *(const half8*)(qrow + quad * 8);
        aq[jsub][1] = *(const half8*)(qrow + 32 + quad * 8);
    }

    float sl[2][4] = {};

    for (int t = 0; t < S / 64; ++t) {
        __syncthreads();                       // tile t staged; buffers swapped
        if (t + 1 < S / 64) stageK((t + 1) & 1, (t + 1) * 64);
        const u16* Kst = Ks[t & 1];
        #pragma unroll
        for (int isub = 0; isub < 4; ++isub) {
            int il = isub * 16 + lr;
            half8 bk0 = *(const half8*)(Kst + il * 64 + (((0 + quad) ^ (il & 7)) * 8));
            half8 bk1 = *(const half8*)(Kst + il * 64 + (((4 + quad) ^ (il & 7)) * 8));
            #pragma unroll
            for (int jsub = 0; jsub < 2; ++jsub) {
                f32x4 c = {0.f, 0.f, 0.f, 0.f};
                c = __builtin_amdgcn_mfma_f32_16x16x32_f16(aq[jsub][0], bk0, c, 0, 0, 0);
                c = __builtin_amdgcn_mfma_f32_16x16x32_f16(aq[jsub][1], bk1, c, 0, 0, 0);
                #pragma unroll
                for (int r = 0; r < 4; ++r) sl[jsub][r] += exp_s(c[r]);
            }
        }
    }

    // C layout: row j = wv*32 + jsub*16 + quad*4 + r; reduce over lr lanes
    #pragma unroll
    for (int jsub = 0; jsub < 2; ++jsub)
        #pragma unroll
        for (int r = 0; r < 4; ++r) {
            float v = sl[jsub][r];
            v += __shfl_xor(v, 1, 64);
            v += __shfl_xor(v, 2, 64);
            v += __shfl_xor(v, 4, 64);
            v += __shfl_xor(v, 8, 64);
            if (lr == 0) rlL[wv * 32 + jsub * 16 + quad * 4 + r] = 1.0f / v;
        }
    __syncthreads();

    // scale Vt[:, jt*128 .. +128] in place; contiguous 64B run per lane-quad
    {
        const int d = tid >> 2, lc = (tid & 3) * 8;
        f16* vrow = Vt + (size_t)(bh * 64 + d) * S + jt * 128;
        #pragma unroll
        for (int g = 0; g < 4; ++g) {
            const int c0 = g * 32 + lc;
            half8 hv = *(half8*)(vrow + c0);
            #pragma unroll
            for (int e = 0; e < 8; ++e)
                hv[e] = (f16)((float)hv[e] * rlL[c0 + e]);
            *(half8*)(vrow + c0) = hv;
        }
    }
}

// ---------------------------------------------------------------------------
// Apply: out[i,d] = sum_{j<=i} exp2(K_i.Q'_j) * V'[j,d]  (V' pre-scaled).
// Double-buffered Q/Vt staging (prefetch before compute).
// ---------------------------------------------------------------------------
__global__ __launch_bounds__(256) void apply_mfma(const f16* __restrict__ Q,
                                                  const f16* __restrict__ K,
                                                  const f16* __restrict__ Vt,
                                                  float* __restrict__ out) {
    const int bh = blockIdx.x;
    const int it2 = (gridDim.y - 1) - blockIdx.y;   // heavy blocks first
    const int b = bh >> 4, h = bh & 15;
    const int tid = threadIdx.x;
    const int wv = tid >> 6, ln = tid & 63;
    const int lr = ln & 15, quad = ln >> 4;
    const int i0b = it2 * 128;
    const int i0w = i0b + wv * 32;

    __shared__ u16 Qs[2][64 * 64];    // 16 KB
    __shared__ u16 Vts[2][64 * 64];   // 16 KB

    auto stageQV = [&](int bufi, int j0v) {
        #pragma unroll
        for (int p = 0; p < 2; ++p) {   // Qs: 64 rows x 64 f16
            int r = p * 32 + (tid >> 3);
            int csw = (tid & 7) ^ (r & 7);
            GLL16(Q + (size_t)(b * S + j0v + r) * HID + h * 64 + csw * 8,
                  Qs[bufi] + p * 2048 + tid * 8);
        }
        #pragma unroll
        for (int p = 0; p < 2; ++p) {   // Vts: 64 d-rows x 64 j
            int d = p * 32 + (tid >> 3);
            int csw = (tid & 7) ^ (d & 7);
            GLL16(Vt + (size_t)(bh * 64 + d) * S + j0v + csw * 8,
                  Vts[bufi] + p * 2048 + tid * 8);
        }
    };

    stageQV(0, 0);   // prefetch chunk 0; hides under the bk loads below

    // K B-fragments (fixed per wave): B[n=i][k], k = kf*32 + quad*8
    half8 bk[2][2];
    #pragma unroll
    for (int isub = 0; isub < 2; ++isub) {
        int i = i0w + isub * 16 + lr;
        #pragma unroll
        for (int kf = 0; kf < 2; ++kf)
            bk[isub][kf] = *(const half8*)(K + (size_t)(b * S + i) * HID + h * 64 +
                                           kf * 32 + quad * 8);
    }

    f32x4 acc[4][2];
    #pragma unroll
    for (int nt = 0; nt < 4; ++nt)
        #pragma unroll
        for (int isub = 0; isub < 2; ++isub) acc[nt][isub] = (f32x4){0.f, 0.f, 0.f, 0.f};

    const int nch = 2 * it2 + 2;
    for (int jc = 0; jc < nch; ++jc) {
        const int j0 = jc * 64;
        __syncthreads();                        // chunk jc staged
        if (jc + 1 < nch) stageQV((jc + 1) & 1, j0 + 64);
        const u16* Qsc = Qs[jc & 1];
        const u16* Vsc = Vts[jc & 1];

        #pragma unroll
        for (int jsub = 0; jsub < 4; ++jsub) {
            const int jbase = j0 + jsub * 16;
            if (jbase > i0w + 31) break;   // this and later jsubs fully masked

            const int jl = jsub * 16 + lr;
            half8 aq0 = *(const half8*)(Qsc + jl * 64 + (((0 + quad) ^ (jl & 7)) * 8));
            half8 aq1 = *(const half8*)(Qsc + jl * 64 + (((4 + quad) ^ (jl & 7)) * 8));
            half4 av[4];
            #pragma unroll
            for (int nt = 0; nt < 4; ++nt) {
                int d = nt * 16 + lr;
                int ch = (jsub * 2 + (quad >> 1)) ^ (d & 7);
                av[nt] = *(const half4*)(Vsc + d * 64 + ch * 8 + (quad & 1) * 4);
            }

            #pragma unroll
            for (int isub = 0; isub < 2; ++isub) {
                const int ib = i0w + isub * 16;
                if (jbase > ib + 15) continue;     // tile fully above diagonal
                f32x4 c = {0.f, 0.f, 0.f, 0.f};
                c = __builtin_amdgcn_mfma_f32_16x16x32_f16(aq0, bk[isub][0], c, 0, 0, 0);
                c = __builtin_amdgcn_mfma_f32_16x16x32_f16(aq1, bk[isub][1], c, 0, 0, 0);
                float w0 = exp_s(c[0]), w1 = exp_s(c[1]);
                float w2 = exp_s(c[2]), w3 = exp_s(c[3]);
                if (jbase + 15 > ib) {             // diagonal tile: mask j > i
                    const int i_col = ib + lr;
                    const int jq = jbase + quad * 4;
                    if (jq + 0 > i_col) w0 = 0.f;
                    if (jq + 1 > i_col) w1 = 0.f;
                    if (jq + 2 > i_col) w2 = 0.f;
                    if (jq + 3 > i_col) w3 = 0.f;
                }
                fp16x2 q0 = __builtin_amdgcn_cvt_pkrtz(w0, w1);
                fp16x2 q1 = __builtin_amdgcn_cvt_pkrtz(w2, w3);
                half2 p0 = __builtin_bit_cast(half2, q0);
                half2 p1 = __builtin_bit_cast(half2, q1);
                half4 bw;
                bw[0] = p0[0]; bw[1] = p0[1]; bw[2] = p1[0]; bw[3] = p1[1];
                #pragma unroll
                for (int nt = 0; nt < 4; ++nt)
                    acc[nt][isub] = __builtin_amdgcn_mfma_f32_16x16x16f16(
                        av[nt], bw, acc[nt][isub], 0, 0, 0);
            }
        }
    }

    // epilogue: acc holds out^T[d][i]; row=d=nt*16+quad*4+r, col=i (lr)
    #pragma unroll
    for (int isub = 0; isub < 2; ++isub) {
        int i = i0w + isub * 16 + lr;
        #pragma unroll
        for (int nt = 0; nt < 4; ++nt)
            *(f32x4*)(out + (size_t)(b * S + i) * HID + h * 64 + nt * 16 + quad * 4) =
                acc[nt][isub];
    }
}

// ---------------------------------------------------------------------------
extern "C" void kernel_launch(void* const* d_in, const int* in_sizes, int n_in,
                              void* d_out, int out_size, void* d_ws, size_t ws_size,
                              hipStream_t stream) {
    const float* q  = (const float*)d_in[0];
    const float* k  = (const float*)d_in[1];
    const float* v  = (const float*)d_in[2];
    const float* Wq = (const float*)d_in[3];
    const float* Wk = (const float*)d_in[4];
    const float* Wv = (const float*)d_in[5];

    const size_t SZ = (size_t)B * S * HID;   // 8,388,608
    const size_t WZ = (size_t)HID * HID;     // 1,048,576

    // q/k f16 casts live inside d_out (32 MB = 2*SZ f16), consumed by proj
    // before apply overwrites d_out. v/W casts + Q/K/Vt live in ws (~70 MB).
    f16* xq = (f16*)d_out;
    f16* xk = xq + SZ;

    char* p = (char*)d_ws;
    f16* xv = (f16*)p;      p += SZ * 2;
    f16* wq = (f16*)p;      p += WZ * 2;
    f16* wk = (f16*)p;      p += WZ * 2;
    f16* wv_ = (f16*)p;     p += WZ * 2;
    f16* Qb = (f16*)p;      p += SZ * 2;
    f16* Kb = (f16*)p;      p += SZ * 2;
    f16* Vt = (f16*)p;      p += SZ * 2;

    float* out = (float*)d_out;

    const int ncast = (int)((3 * SZ + 3 * WZ) / 8 / 256);   // 13824 blocks
    cast_all<<<ncast, 256, 0, stream>>>(q, k, v, Wq, Wk, Wv,
                                        xq, xk, xv, wq, wk, wv_);

    // 3 GEMMs in one 768-block launch (256x128 tiles), XCD-swizzled
    proj_mfma_b<<<768, 512, 0, stream>>>(xq, xk, xv, wq, wk, wv_, Qb, Kb, Vt);

    stats_mfma<<<dim3(B * HEADS, S / 128), 256, 0, stream>>>(Qb, Kb, Vt);
    apply_mfma<<<dim3(B * HEADS, S / 128), 256, 0, stream>>>(Qb, Kb, Vt, out);
}